// Round 9
// baseline (62.557 us; speedup 1.0000x reference)
//
#include <hip/hip_runtime.h>
#include <stdint.h>

#define V 50257
#define B_ 64
#define S_ 8
#define ROWS (B_ * S_)
#define L_ 2048
#define NEG_INF -1000000000.0f
#define PEN_NEG (-1200000000.0f)   // NEG_INF * 1.2f, exact in fp32
#define MASK_WORDS_PER_B 1571      // ceil(50257/32)
#define TOTAL (ROWS * V)           // 25,731,584
#define NVEC (TOTAL / 4)           // 6,432,896 (exact)
#define TOP_CAP 64                 // top-k=50 plus headroom for exact ties at kth
#define TRAW 2.8f                  // raw cutoff; E[cnt]=128/row, P(cnt<50)~1e-14
#define GBLK_F4 1571               // float4s per prep block (spans <= 2 rows)
#define GBLOCKS_G ((NVEC + GBLK_F4 - 1) / GBLK_F4)   // 4095
#define GCAP_BLK 64                // per-block candidate region (mean 16, sd 4)
#define CAPROW 512                 // per-row candidate cap in select
#define NPRESW ((GBLK_F4 * 4 + 31) / 32)             // 197 words range-presence

typedef __attribute__((ext_vector_type(4))) float f32x4;

// ---- workspace layout ----
#define WS_BCNT    0                                    // 4095 u32 -> pad 16384
#define WS_GCAND   16384                                // 4095*64*8 = 2,096,640
#define WS_NEED    (WS_GCAND + (size_t)GBLOCKS_G * GCAP_BLK * 8)   // ~2.11 MB
// fallback layout (disjoint use; only when ws too small for fast path)
#define WS_ROWPARAM 0                                   // 512 * 16 B
#define WS_MASK     8192                                // 402176 B

__device__ __forceinline__ unsigned fkey(float f) {
    unsigned u = __float_as_uint(f);
    return (u & 0x80000000u) ? ~u : (u | 0x80000000u);
}

__device__ __forceinline__ int blockReduceSum256(int v, int tid, int* s4) {
#pragma unroll
    for (int off = 32; off; off >>= 1) v += __shfl_down(v, off);
    __syncthreads();
    if ((tid & 63) == 0) s4[tid >> 6] = v;
    __syncthreads();
    return s4[0] + s4[1] + s4[2] + s4[3];
}

// ---------------- prep: presence first, then barrier-free streaming ----------------

// Block owns f4 range [blk*GBLK_F4, end). Phase 1: presence bits (ids) +
// barrier. Phase 2 (NO barriers): issue 7 loads, consume -> gather candidates
// into LDS + write output background (nt stores). Phase 3: barrier + publish
// private gcand region with a plain count store (no global atomics anywhere).
__global__ __launch_bounds__(256) void prep_kernel(const float4* __restrict__ in4,
                                                   const int* __restrict__ ids,
                                                   float4* __restrict__ out4,
                                                   uint2* __restrict__ gcand,
                                                   unsigned* __restrict__ bcnt) {
    const int blk = blockIdx.x;
    const int tid = threadIdx.x;
    const int start = blk * GBLK_F4;
    const int end = min(start + GBLK_F4, NVEC);
    const unsigned baseE = (unsigned)start << 2;
    const unsigned endE = (unsigned)end << 2;

    __shared__ unsigned pres[NPRESW];
    __shared__ uint2 buf[GCAP_BLK];
    __shared__ int lcnt;

    // ---- phase 1: presence bits from the (at most one) s==7 row in range ----
    for (int w = tid; w < NPRESW; w += 256) pres[w] = 0u;
    if (tid == 0) lcnt = 0;
    {
        unsigned r0 = baseE / (unsigned)V, r1 = (endE - 1u) / (unsigned)V;
        unsigned rl = ((r0 & 7u) == 7u) ? r0 : (((r1 & 7u) == 7u) ? r1 : 0xFFFFFFFFu);
        if (rl != 0xFFFFFFFFu) {
            __syncthreads();   // pres zero visible before atomicOr
            const int* bp = ids + (rl >> 3) * L_;
            unsigned rowBase = rl * (unsigned)V;
#pragma unroll
            for (int k = 0; k < L_ / 256; ++k) {
                unsigned ge = rowBase + (unsigned)bp[k * 256 + tid];
                if (ge >= baseE && ge < endE) {
                    unsigned off = ge - baseE;
                    atomicOr(&pres[off >> 5], 1u << (off & 31));
                }
            }
        }
    }
    __syncthreads();   // only pre-stream barrier (drains only the tiny ids loads)

    // ---- phase 2: barrier-free stream: 7 loads issued, then consumed ----
    float4 va0 = in4[min(start + tid,            NVEC - 1)];
    float4 va1 = in4[min(start + tid + 256,      NVEC - 1)];
    float4 va2 = in4[min(start + tid + 2 * 256,  NVEC - 1)];
    float4 va3 = in4[min(start + tid + 3 * 256,  NVEC - 1)];
    float4 va4 = in4[min(start + tid + 4 * 256,  NVEC - 1)];
    float4 va5 = in4[min(start + tid + 5 * 256,  NVEC - 1)];
    float4 va6 = in4[min(start + tid + 6 * 256,  NVEC - 1)];
    float4 va[7] = {va0, va1, va2, va3, va4, va5, va6};
#pragma unroll
    for (int k = 0; k < 7; ++k) {
        int i = start + tid + k * 256;
        if (i < end) {
            float4 a = va[k];
            unsigned e = (unsigned)i << 2;
            if (a.x >= TRAW) { int p = atomicAdd(&lcnt, 1); if (p < GCAP_BLK) buf[p] = make_uint2(e,      __float_as_uint(a.x)); }
            if (a.y >= TRAW) { int p = atomicAdd(&lcnt, 1); if (p < GCAP_BLK) buf[p] = make_uint2(e + 1u, __float_as_uint(a.y)); }
            if (a.z >= TRAW) { int p = atomicAdd(&lcnt, 1); if (p < GCAP_BLK) buf[p] = make_uint2(e + 2u, __float_as_uint(a.z)); }
            if (a.w >= TRAW) { int p = atomicAdd(&lcnt, 1); if (p < GCAP_BLK) buf[p] = make_uint2(e + 3u, __float_as_uint(a.w)); }
            unsigned off = e - baseE;              // off % 4 == 0 -> 4 bits in one word
            unsigned pw = pres[off >> 5] >> (off & 31u);
            f32x4 bg;
            bg.x = (pw & 1u) ? PEN_NEG : NEG_INF;
            bg.y = (pw & 2u) ? PEN_NEG : NEG_INF;
            bg.z = (pw & 4u) ? PEN_NEG : NEG_INF;
            bg.w = (pw & 8u) ? PEN_NEG : NEG_INF;
            __builtin_nontemporal_store(bg, (f32x4*)&out4[i]);   // don't evict logits from L3
        }
    }

    // ---- phase 3: publish candidates ----
    __syncthreads();
    if (tid == 0) bcnt[blk] = (unsigned)lcnt;      // > GCAP_BLK flags overflow
    int take = min(lcnt, GCAP_BLK);
    for (int j = tid; j < take; j += 256) gcand[(size_t)blk * GCAP_BLK + j] = buf[j];
}

// ---------------- select: exact per-row threshold + scatter of kept values ----------------

// One 256-thread block per row. Exact reference semantics incl. fp32 ties:
// kth = 50th largest of x=v/0.8f; kept = ALL x >= kth; stable (x desc, idx asc)
// order like np.argsort(-x); f64 softmax+cumsum decision. Then scatters the
// kept values (x, with rep-penalty for s==7 rows) over prep's background.
__global__ __launch_bounds__(256) void select_kernel(const float* __restrict__ logits,
                                                     const int* __restrict__ ids,
                                                     const uint2* __restrict__ gcand,
                                                     const unsigned* __restrict__ bcnt,
                                                     float* __restrict__ out) {
    const int row = blockIdx.x;
    const int tid = threadIdx.x;
    __shared__ float cX[CAPROW];
    __shared__ unsigned cR[CAPROW];
    __shared__ int cI[CAPROW];
    __shared__ float sVal[TOP_CAP];
    __shared__ int sIdx[TOP_CAP];
    __shared__ double sExp[TOP_CAP];
    __shared__ unsigned presRow[MASK_WORDS_PER_B];
    __shared__ int s_c, s_M, s_bad, s_ti;
    __shared__ float s_t;
    __shared__ int s_red[4];

    const float* rp = logits + (size_t)row * V;
    const unsigned e0 = (unsigned)row * (unsigned)V;
    if (tid == 0) { s_c = 0; s_bad = 0; }
    __syncthreads();

    {   // scan the <=9 prep-block regions overlapping this row; filter by row
        const int b0 = (int)((e0 >> 2) / GBLK_F4);
        const int b1 = (int)(((e0 + V - 1) >> 2) / GBLK_F4);
        for (int blk = b0; blk <= b1; ++blk) {
            unsigned c = bcnt[blk];
            if (c > GCAP_BLK && tid == 0) s_bad = 1;
            int take = min((int)c, GCAP_BLK);
            for (int j = tid; j < take; j += 256) {
                uint2 u = gcand[(size_t)blk * GCAP_BLK + j];
                if (u.x / (unsigned)V == (unsigned)row) {
                    int p = atomicAdd(&s_c, 1);
                    if (p < CAPROW) {
                        cR[p] = u.y;
                        cX[p] = __uint_as_float(u.y) / 0.8f;
                        cI[p] = (int)(u.x - e0);
                    }
                }
            }
        }
    }
    __syncthreads();
    int cnt = s_c;
    if (s_bad || cnt < 50 || cnt > CAPROW) {
        // Pathological-only exact fallback: bisect raw key space for the 50th
        // largest, re-gather with 2-ulp slack (covers /0.8 merging distinct raws).
        unsigned lo = 0u, hi = 0xFFFFFFFFu;
        while (lo < hi) {
            unsigned mid = lo + ((hi - lo) >> 1) + 1u;
            int c = 0;
            for (int j = tid; j < V; j += 256) c += (int)(fkey(rp[j]) >= mid);
            c = blockReduceSum256(c, tid, s_red);
            if (c >= 50) lo = mid; else hi = mid - 1u;
        }
        unsigned gl = (lo > 2u) ? lo - 2u : 0u;
        __syncthreads();
        if (tid == 0) s_c = 0;
        __syncthreads();
        for (int j = tid; j < V; j += 256) {
            float v = rp[j];
            if (fkey(v) >= gl) {
                int p = atomicAdd(&s_c, 1);
                if (p < CAPROW) { cR[p] = __float_as_uint(v); cX[p] = v / 0.8f; cI[p] = j; }
            }
        }
        __syncthreads();
        cnt = min(s_c, CAPROW);
    }

    if (tid < TOP_CAP) { sVal[tid] = -3.4e38f; sIdx[tid] = 0x7FFFFFFF; }
    __syncthreads();

    // Rank-sort: each thread owns <=2 candidates; j-loop is an LDS broadcast
    // read (conflict-free). Ranks unique via (x desc, token idx asc) key.
    {
        float v0 = -3.4e38f, v1 = -3.4e38f;
        int i0 = 0x7FFFFFFF, i1 = 0x7FFFFFFF;
        if (tid < cnt) { v0 = cX[tid]; i0 = cI[tid]; }
        if (tid + 256 < cnt) { v1 = cX[tid + 256]; i1 = cI[tid + 256]; }
        int r0 = 0, r1 = 0;
        for (int j = 0; j < cnt; ++j) {
            float w = cX[j];
            int wi = cI[j];
            r0 += (w > v0) || (w == v0 && wi < i0);
            r1 += (w > v1) || (w == v1 && wi < i1);
        }
        if (tid < cnt && r0 < TOP_CAP) { sVal[r0] = v0; sIdx[r0] = i0; }
        if (tid + 256 < cnt && r1 < TOP_CAP) { sVal[r1] = v1; sIdx[r1] = i1; }
    }
    __syncthreads();

    if (tid == 0) {
        float kth = sVal[49];
        int M = 50;
        while (M < TOP_CAP && sVal[M] == kth) ++M;   // include exact ties at kth
        s_M = M;
    }
    __syncthreads();
    int M = s_M;
    if (tid < M) sExp[tid] = exp((double)sVal[tid] - (double)sVal[0]);
    __syncthreads();
    if (tid == 0) {
        double denom = 0.0;
        for (int i = 0; i < M; ++i) denom += sExp[i];
        double cum = 0.0;
        int J = M - 1;
        for (int i = 0; i < M; ++i) {
            cum += sExp[i] / denom;
            if (cum > 0.9) { J = i; break; }
        }
        s_t = sVal[J];
        s_ti = sIdx[J];
    }

    // presence bitmask for the rep-penalty (only s==7 rows; block-uniform branch)
    if ((row & 7) == 7) {
        __syncthreads();
        for (int w = tid; w < MASK_WORDS_PER_B; w += 256) presRow[w] = 0u;
        __syncthreads();
        const int* bp = ids + (row >> 3) * L_;
#pragma unroll
        for (int k = 0; k < L_ / 256; ++k) {
            int t = bp[k * 256 + tid];
            atomicOr(&presRow[t >> 5], 1u << (t & 31));
        }
    }
    __syncthreads();

    // scatter kept values over the background (kept set is always a subset of
    // the candidate set: t >= kth >= TRAW/0.8 on the non-fallback path)
    float t = s_t;
    int tie = s_ti;
    float* orow = out + (size_t)row * V;
    const bool pen = (row & 7) == 7;
    for (int j = tid; j < cnt; j += 256) {
        float x = cX[j];
        int tok = cI[j];
        bool keep = (x > t) || (x == t && tok <= tie);
        if (keep) {
            float oo = x;   // exact v/0.8f, matches reference bits
            if (pen && ((presRow[tok >> 5] >> (tok & 31)) & 1u))
                oo = (oo < 0.0f) ? oo * 1.2f : oo * (1.0f / 1.2f);
            orow[tok] = oo;
        }
    }
}

// ---------------- safety fallback (ws too small; proven 3-kernel path) ----------------
#define CAND_CAP 4096
#define RT_THREADS 1024

__global__ __launch_bounds__(256) void mask_only_kernel(const int* __restrict__ ids,
                                                        unsigned* __restrict__ mask) {
    const int tid = threadIdx.x;
    const int b = blockIdx.x;
    __shared__ unsigned lds[MASK_WORDS_PER_B];
    for (int w = tid; w < MASK_WORDS_PER_B; w += 256) lds[w] = 0u;
    __syncthreads();
    const int* bp = ids + b * L_;
#pragma unroll
    for (int k = 0; k < L_ / 256; ++k) {
        int t = bp[k * 256 + tid];
        atomicOr(&lds[t >> 5], 1u << (t & 31));
    }
    __syncthreads();
    unsigned* mp = mask + b * MASK_WORDS_PER_B;
    for (int w = tid; w < MASK_WORDS_PER_B; w += 256) mp[w] = lds[w];
}

__global__ __launch_bounds__(RT_THREADS, 8) void row_thresh_kernel(
        const float* __restrict__ logits, uint4* __restrict__ rowParam) {
    const int tid = threadIdx.x;
    const int row = blockIdx.x;
    if (row >= ROWS) return;
    const float* rp = logits + (size_t)row * V;

    __shared__ float candV[CAND_CAP];
    __shared__ int   candI[CAND_CAP];
    __shared__ float sVal[TOP_CAP];
    __shared__ int   sIdx[TOP_CAP];
    __shared__ double sExp[TOP_CAP];
    __shared__ int s_cnt, s_M;
    __shared__ int s_red[RT_THREADS / 64];

    const unsigned mis = (unsigned)(((size_t)row * (size_t)V) & 3u);
    const int a0 = (int)((4u - mis) & 3u);
    const int nv = (V - a0) >> 2;
    const int tailStart = a0 + (nv << 2);
    const float4* vp = reinterpret_cast<const float4*>(rp + a0);

    float TR = 2.4f;
    int cnt = 0;
    for (int attempt = 0; attempt < 12; ++attempt) {
        if (tid == 0) s_cnt = 0;
        __syncthreads();
        for (int base = tid; base < nv; base += 4 * RT_THREADS) {
            int i1 = base + RT_THREADS, i2 = base + 2 * RT_THREADS, i3 = base + 3 * RT_THREADS;
            float4 a = vp[base];
            float4 b = vp[i1 < nv ? i1 : nv - 1];
            float4 c = vp[i2 < nv ? i2 : nv - 1];
            float4 d = vp[i3 < nv ? i3 : nv - 1];
            float va[16] = {a.x, a.y, a.z, a.w, b.x, b.y, b.z, b.w,
                            c.x, c.y, c.z, c.w, d.x, d.y, d.z, d.w};
            int ib[4] = {base, i1, i2, i3};
            bool ok[4] = {true, i1 < nv, i2 < nv, i3 < nv};
#pragma unroll
            for (int q = 0; q < 4; ++q) {
                if (!ok[q]) continue;
#pragma unroll
                for (int cc = 0; cc < 4; ++cc) {
                    float v = va[q * 4 + cc];
                    if (v >= TR) {
                        int p = atomicAdd(&s_cnt, 1);
                        if (p < CAND_CAP) { candV[p] = v / 0.8f; candI[p] = a0 + (ib[q] << 2) + cc; }
                    }
                }
            }
        }
        if (tid < a0) {
            float v = rp[tid];
            if (v >= TR) {
                int p = atomicAdd(&s_cnt, 1);
                if (p < CAND_CAP) { candV[p] = v / 0.8f; candI[p] = tid; }
            }
        }
        if (tid < V - tailStart) {
            float v = rp[tailStart + tid];
            if (v >= TR) {
                int p = atomicAdd(&s_cnt, 1);
                if (p < CAND_CAP) { candV[p] = v / 0.8f; candI[p] = tailStart + tid; }
            }
        }
        __syncthreads();
        cnt = s_cnt;
        if (cnt >= 50 && cnt <= CAND_CAP) break;
        if (cnt < 50) TR -= 1.2f; else TR += 1.2f;
        __syncthreads();
    }
    if (cnt > CAND_CAP) cnt = CAND_CAP;

    if (tid < TOP_CAP) { sVal[tid] = -3.4e38f; sIdx[tid] = 0x7FFFFFFF; }
    __syncthreads();

    {
        float v0 = (tid < cnt) ? candV[tid] : -3.4e38f;
        int i0 = (tid < cnt) ? candI[tid] : 0x7FFFFFFF;
        float v1 = (tid + RT_THREADS < cnt) ? candV[tid + RT_THREADS] : -3.4e38f;
        int i1 = (tid + RT_THREADS < cnt) ? candI[tid + RT_THREADS] : 0x7FFFFFFF;
        float v2 = (tid + 2 * RT_THREADS < cnt) ? candV[tid + 2 * RT_THREADS] : -3.4e38f;
        int i2 = (tid + 2 * RT_THREADS < cnt) ? candI[tid + 2 * RT_THREADS] : 0x7FFFFFFF;
        float v3 = (tid + 3 * RT_THREADS < cnt) ? candV[tid + 3 * RT_THREADS] : -3.4e38f;
        int i3 = (tid + 3 * RT_THREADS < cnt) ? candI[tid + 3 * RT_THREADS] : 0x7FFFFFFF;
        int r0 = 0, r1 = 0, r2 = 0, r3 = 0;
        for (int j = 0; j < cnt; ++j) {
            float w = candV[j];
            int wi = candI[j];
            r0 += (w > v0) || (w == v0 && wi < i0);
            r1 += (w > v1) || (w == v1 && wi < i1);
            r2 += (w > v2) || (w == v2 && wi < i2);
            r3 += (w > v3) || (w == v3 && wi < i3);
        }
        if (tid < cnt && r0 < TOP_CAP) { sVal[r0] = v0; sIdx[r0] = i0; }
        if (tid + RT_THREADS < cnt && r1 < TOP_CAP) { sVal[r1] = v1; sIdx[r1] = i1; }
        if (tid + 2 * RT_THREADS < cnt && r2 < TOP_CAP) { sVal[r2] = v2; sIdx[r2] = i2; }
        if (tid + 3 * RT_THREADS < cnt && r3 < TOP_CAP) { sVal[r3] = v3; sIdx[r3] = i3; }
    }
    __syncthreads();

    if (tid == 0) {
        float kth = sVal[49];
        int M = 50;
        while (M < TOP_CAP && sVal[M] == kth) ++M;
        s_M = M;
    }
    __syncthreads();
    int M = s_M;
    if (tid < M) sExp[tid] = exp((double)sVal[tid] - (double)sVal[0]);
    __syncthreads();

    if (tid == 0) {
        double denom = 0.0;
#pragma unroll 1
        for (int i = 0; i < M; ++i) denom += sExp[i];
        double cum = 0.0;
        int J = M - 1;
#pragma unroll 1
        for (int i = 0; i < M; ++i) {
            cum += sExp[i] / denom;
            if (cum > 0.9) { J = i; break; }
        }
        float t = sVal[J];
        float w = t * 0.8f;
        unsigned wb = __float_as_uint(w);
        unsigned lo = 0xFFFFFFFFu, hi = 0u;
        for (int d = -4; d <= 4; ++d) {
            unsigned ub = wb + (unsigned)d;
            if (__uint_as_float(ub) / 0.8f == t) { if (ub < lo) lo = ub; if (ub > hi) hi = ub; }
        }
        rowParam[row] = make_uint4(lo, hi, (unsigned)sIdx[J], 0u);
    }
}

__global__ __launch_bounds__(256) void apply_kernel(const float4* __restrict__ in4,
                                                    const uint4* __restrict__ rowParam,
                                                    const unsigned* __restrict__ mask,
                                                    float4* __restrict__ out4) {
    int gid = blockIdx.x * 256 + threadIdx.x;
    int i0 = gid << 1;
    if (i0 >= NVEC) return;
    float4 a = in4[i0];
    float4 b = in4[i0 + 1];
    unsigned e = (unsigned)i0 << 2;
    unsigned row = e / (unsigned)V;
    unsigned tok0 = e - row * (unsigned)V;
    uint4 p0 = rowParam[row];
    bool crosses = (tok0 + 7u >= (unsigned)V);
    uint4 p1 = crosses ? rowParam[row + 1] : p0;
    float xs[8] = {a.x, a.y, a.z, a.w, b.x, b.y, b.z, b.w};
    float o[8];
#pragma unroll
    for (int c = 0; c < 8; ++c) {
        unsigned tok = tok0 + (unsigned)c;
        unsigned r = row;
        uint4 pp = p0;
        if (tok >= (unsigned)V) { tok -= (unsigned)V; r = row + 1u; pp = p1; }
        float v = xs[c];
        float vlo = __uint_as_float(pp.x);
        float vhi = __uint_as_float(pp.y);
        bool keep = (v > vhi) || (v >= vlo && tok <= pp.z);
        float oo = keep ? v * 1.25f : NEG_INF;
        if ((r & 7u) == 7u) {
            unsigned w = mask[(r >> 3) * MASK_WORDS_PER_B + (tok >> 5)];
            if ((w >> (tok & 31u)) & 1u) oo = (oo < 0.0f) ? oo * 1.2f : oo * (1.0f / 1.2f);
        }
        o[c] = oo;
    }
    out4[i0] = make_float4(o[0], o[1], o[2], o[3]);
    out4[i0 + 1] = make_float4(o[4], o[5], o[6], o[7]);
}

extern "C" void kernel_launch(void* const* d_in, const int* in_sizes, int n_in,
                              void* d_out, int out_size, void* d_ws, size_t ws_size,
                              hipStream_t stream) {
    const float* logits = (const float*)d_in[0];
    const int* ids = (const int*)d_in[1];
    float* out = (float*)d_out;

    if (ws_size >= WS_NEED) {
        unsigned* bcnt = (unsigned*)((char*)d_ws + WS_BCNT);
        uint2* gcand = (uint2*)((char*)d_ws + WS_GCAND);
        // 2-kernel fast path: prep (stream read + background write, barrier-free
        // hot loop) -> select (exact threshold + scatter kept values)
        prep_kernel<<<GBLOCKS_G, 256, 0, stream>>>((const float4*)logits, ids, (float4*)out,
                                                   gcand, bcnt);
        select_kernel<<<ROWS, 256, 0, stream>>>(logits, ids, gcand, bcnt, out);
    } else {
        uint4* rowParam = (uint4*)((char*)d_ws + WS_ROWPARAM);
        unsigned* mask = (unsigned*)((char*)d_ws + WS_MASK);
        mask_only_kernel<<<B_, 256, 0, stream>>>(ids, mask);
        row_thresh_kernel<<<ROWS, RT_THREADS, 0, stream>>>(logits, rowParam);
        apply_kernel<<<(NVEC / 2 + 255) / 256, 256, 0, stream>>>((const float4*)logits, rowParam,
                                                                 mask, (float4*)out);
    }
}

// Round 10
// 61.207 us; speedup vs baseline: 1.0221x; 1.0221x over previous
//
#include <hip/hip_runtime.h>
#include <stdint.h>

#define V 50257
#define B_ 64
#define S_ 8
#define ROWS (B_ * S_)
#define L_ 2048
#define NEG_INF -1000000000.0f
#define PEN_NEG (-1200000000.0f)   // NEG_INF * 1.2f, exact in fp32
#define MASK_WORDS_PER_B 1571      // ceil(50257/32)
#define TOTAL (ROWS * V)           // 25,731,584
#define NVEC (TOTAL / 4)           // 6,432,896 (exact)
#define TOP_CAP 64                 // top-k=50 plus headroom for exact ties at kth
#define TRAW 2.8f                  // raw cutoff; E[cnt]=128/row, P(cnt<50)~1e-14
#define GBLK_F4 1571               // float4s per prep block (spans <= 2 rows)
#define GBLOCKS_G ((NVEC + GBLK_F4 - 1) / GBLK_F4)   // 4095
#define GCAP_BLK 64                // per-block candidate region (mean 16, sd 4)
#define CAPROW 512                 // per-row candidate cap in select
#define NPRESW ((GBLK_F4 * 4 + 31) / 32)             // 197 words range-presence

// ---- workspace layout ----
#define WS_BCNT    0                                    // 4095 u32 -> pad 16384
#define WS_GCAND   16384                                // 4095*64*8 = 2,096,640
#define WS_NEED    (WS_GCAND + (size_t)GBLOCKS_G * GCAP_BLK * 8)   // ~2.11 MB
// fallback layout (disjoint use; only when ws too small for fast path)
#define WS_ROWPARAM 0                                   // 512 * 16 B
#define WS_MASK     8192                                // 402176 B

__device__ __forceinline__ unsigned fkey(float f) {
    unsigned u = __float_as_uint(f);
    return (u & 0x80000000u) ? ~u : (u | 0x80000000u);
}

__device__ __forceinline__ int blockReduceSum256(int v, int tid, int* s4) {
#pragma unroll
    for (int off = 32; off; off >>= 1) v += __shfl_down(v, off);
    __syncthreads();
    if ((tid & 63) == 0) s4[tid >> 6] = v;
    __syncthreads();
    return s4[0] + s4[1] + s4[2] + s4[3];
}

// ---------------- prep: presence first, then pinned-MLP streaming ----------------

// Block owns f4 range [blk*GBLK_F4, end). Phase 1: presence bits (ids) +
// barrier. Phase 2: issue ALL 7 loads, then sched_barrier(0) pins them above
// the consume code (compiler otherwise sinks loads to uses -> 1 outstanding
// load/wave -> 2.8 TB/s; with 7 outstanding -> BW-bound). Phase 3: barrier +
// publish private gcand region with a plain count store (no global atomics).
__global__ __launch_bounds__(256) void prep_kernel(const float4* __restrict__ in4,
                                                   const int* __restrict__ ids,
                                                   float4* __restrict__ out4,
                                                   uint2* __restrict__ gcand,
                                                   unsigned* __restrict__ bcnt) {
    const int blk = blockIdx.x;
    const int tid = threadIdx.x;
    const int start = blk * GBLK_F4;
    const int end = min(start + GBLK_F4, NVEC);
    const unsigned baseE = (unsigned)start << 2;
    const unsigned endE = (unsigned)end << 2;

    __shared__ unsigned pres[NPRESW];
    __shared__ uint2 buf[GCAP_BLK];
    __shared__ int lcnt;

    // ---- phase 1: presence bits from the (at most one) s==7 row in range ----
    for (int w = tid; w < NPRESW; w += 256) pres[w] = 0u;
    if (tid == 0) lcnt = 0;
    {
        unsigned r0 = baseE / (unsigned)V, r1 = (endE - 1u) / (unsigned)V;
        unsigned rl = ((r0 & 7u) == 7u) ? r0 : (((r1 & 7u) == 7u) ? r1 : 0xFFFFFFFFu);
        if (rl != 0xFFFFFFFFu) {
            __syncthreads();   // pres zero visible before atomicOr
            const int* bp = ids + (rl >> 3) * L_;
            unsigned rowBase = rl * (unsigned)V;
#pragma unroll
            for (int k = 0; k < L_ / 256; ++k) {
                unsigned ge = rowBase + (unsigned)bp[k * 256 + tid];
                if (ge >= baseE && ge < endE) {
                    unsigned off = ge - baseE;
                    atomicOr(&pres[off >> 5], 1u << (off & 31));
                }
            }
        }
    }
    __syncthreads();   // only pre-stream barrier

    // ---- phase 2: issue all 7 loads, pin them, then consume ----
    float4 va0 = in4[min(start + tid,            NVEC - 1)];
    float4 va1 = in4[min(start + tid + 256,      NVEC - 1)];
    float4 va2 = in4[min(start + tid + 2 * 256,  NVEC - 1)];
    float4 va3 = in4[min(start + tid + 3 * 256,  NVEC - 1)];
    float4 va4 = in4[min(start + tid + 4 * 256,  NVEC - 1)];
    float4 va5 = in4[min(start + tid + 5 * 256,  NVEC - 1)];
    float4 va6 = in4[min(start + tid + 6 * 256,  NVEC - 1)];
    __builtin_amdgcn_sched_barrier(0);   // nothing crosses: all 7 loads issue first
    float4 va[7] = {va0, va1, va2, va3, va4, va5, va6};
#pragma unroll
    for (int k = 0; k < 7; ++k) {
        int i = start + tid + k * 256;
        if (i < end) {
            float4 a = va[k];
            unsigned e = (unsigned)i << 2;
            if (a.x >= TRAW) { int p = atomicAdd(&lcnt, 1); if (p < GCAP_BLK) buf[p] = make_uint2(e,      __float_as_uint(a.x)); }
            if (a.y >= TRAW) { int p = atomicAdd(&lcnt, 1); if (p < GCAP_BLK) buf[p] = make_uint2(e + 1u, __float_as_uint(a.y)); }
            if (a.z >= TRAW) { int p = atomicAdd(&lcnt, 1); if (p < GCAP_BLK) buf[p] = make_uint2(e + 2u, __float_as_uint(a.z)); }
            if (a.w >= TRAW) { int p = atomicAdd(&lcnt, 1); if (p < GCAP_BLK) buf[p] = make_uint2(e + 3u, __float_as_uint(a.w)); }
            unsigned off = e - baseE;              // off % 4 == 0 -> 4 bits in one word
            unsigned pw = pres[off >> 5] >> (off & 31u);
            float4 bg;
            bg.x = (pw & 1u) ? PEN_NEG : NEG_INF;
            bg.y = (pw & 2u) ? PEN_NEG : NEG_INF;
            bg.z = (pw & 4u) ? PEN_NEG : NEG_INF;
            bg.w = (pw & 8u) ? PEN_NEG : NEG_INF;
            out4[i] = bg;
        }
    }

    // ---- phase 3: publish candidates ----
    __syncthreads();
    if (tid == 0) bcnt[blk] = (unsigned)lcnt;      // > GCAP_BLK flags overflow
    int take = min(lcnt, GCAP_BLK);
    for (int j = tid; j < take; j += 256) gcand[(size_t)blk * GCAP_BLK + j] = buf[j];
}

// ---------------- select: exact per-row threshold + scatter of kept values ----------------

// One 256-thread block per row. Exact reference semantics incl. fp32 ties:
// kth = 50th largest of x=v/0.8f; kept = ALL x >= kth; stable (x desc, idx asc)
// order like np.argsort(-x); f64 softmax+cumsum decision. Then scatters the
// kept values (x, with rep-penalty for s==7 rows) over prep's background.
__global__ __launch_bounds__(256) void select_kernel(const float* __restrict__ logits,
                                                     const int* __restrict__ ids,
                                                     const uint2* __restrict__ gcand,
                                                     const unsigned* __restrict__ bcnt,
                                                     float* __restrict__ out) {
    const int row = blockIdx.x;
    const int tid = threadIdx.x;
    __shared__ float cX[CAPROW];
    __shared__ unsigned cR[CAPROW];
    __shared__ int cI[CAPROW];
    __shared__ float sVal[TOP_CAP];
    __shared__ int sIdx[TOP_CAP];
    __shared__ double sExp[TOP_CAP];
    __shared__ unsigned presRow[MASK_WORDS_PER_B];
    __shared__ int s_c, s_M, s_bad, s_ti;
    __shared__ float s_t;
    __shared__ int s_red[4];

    const float* rp = logits + (size_t)row * V;
    const unsigned e0 = (unsigned)row * (unsigned)V;
    if (tid == 0) { s_c = 0; s_bad = 0; }
    __syncthreads();

    {   // scan the <=9 prep-block regions overlapping this row; filter by row
        const int b0 = (int)((e0 >> 2) / GBLK_F4);
        const int b1 = (int)(((e0 + V - 1) >> 2) / GBLK_F4);
        for (int blk = b0; blk <= b1; ++blk) {
            unsigned c = bcnt[blk];
            if (c > GCAP_BLK && tid == 0) s_bad = 1;
            int take = min((int)c, GCAP_BLK);
            for (int j = tid; j < take; j += 256) {
                uint2 u = gcand[(size_t)blk * GCAP_BLK + j];
                if (u.x / (unsigned)V == (unsigned)row) {
                    int p = atomicAdd(&s_c, 1);
                    if (p < CAPROW) {
                        cR[p] = u.y;
                        cX[p] = __uint_as_float(u.y) / 0.8f;
                        cI[p] = (int)(u.x - e0);
                    }
                }
            }
        }
    }
    __syncthreads();
    int cnt = s_c;
    if (s_bad || cnt < 50 || cnt > CAPROW) {
        // Pathological-only exact fallback: bisect raw key space for the 50th
        // largest, re-gather with 2-ulp slack (covers /0.8 merging distinct raws).
        unsigned lo = 0u, hi = 0xFFFFFFFFu;
        while (lo < hi) {
            unsigned mid = lo + ((hi - lo) >> 1) + 1u;
            int c = 0;
            for (int j = tid; j < V; j += 256) c += (int)(fkey(rp[j]) >= mid);
            c = blockReduceSum256(c, tid, s_red);
            if (c >= 50) lo = mid; else hi = mid - 1u;
        }
        unsigned gl = (lo > 2u) ? lo - 2u : 0u;
        __syncthreads();
        if (tid == 0) s_c = 0;
        __syncthreads();
        for (int j = tid; j < V; j += 256) {
            float v = rp[j];
            if (fkey(v) >= gl) {
                int p = atomicAdd(&s_c, 1);
                if (p < CAPROW) { cR[p] = __float_as_uint(v); cX[p] = v / 0.8f; cI[p] = j; }
            }
        }
        __syncthreads();
        cnt = min(s_c, CAPROW);
    }

    if (tid < TOP_CAP) { sVal[tid] = -3.4e38f; sIdx[tid] = 0x7FFFFFFF; }
    __syncthreads();

    // Rank-sort: each thread owns <=2 candidates; j-loop is an LDS broadcast
    // read (conflict-free). Ranks unique via (x desc, token idx asc) key.
    {
        float v0 = -3.4e38f, v1 = -3.4e38f;
        int i0 = 0x7FFFFFFF, i1 = 0x7FFFFFFF;
        if (tid < cnt) { v0 = cX[tid]; i0 = cI[tid]; }
        if (tid + 256 < cnt) { v1 = cX[tid + 256]; i1 = cI[tid + 256]; }
        int r0 = 0, r1 = 0;
        for (int j = 0; j < cnt; ++j) {
            float w = cX[j];
            int wi = cI[j];
            r0 += (w > v0) || (w == v0 && wi < i0);
            r1 += (w > v1) || (w == v1 && wi < i1);
        }
        if (tid < cnt && r0 < TOP_CAP) { sVal[r0] = v0; sIdx[r0] = i0; }
        if (tid + 256 < cnt && r1 < TOP_CAP) { sVal[r1] = v1; sIdx[r1] = i1; }
    }
    __syncthreads();

    if (tid == 0) {
        float kth = sVal[49];
        int M = 50;
        while (M < TOP_CAP && sVal[M] == kth) ++M;   // include exact ties at kth
        s_M = M;
    }
    __syncthreads();
    int M = s_M;
    if (tid < M) sExp[tid] = exp((double)sVal[tid] - (double)sVal[0]);
    __syncthreads();
    if (tid == 0) {
        double denom = 0.0;
        for (int i = 0; i < M; ++i) denom += sExp[i];
        double cum = 0.0;
        int J = M - 1;
        for (int i = 0; i < M; ++i) {
            cum += sExp[i] / denom;
            if (cum > 0.9) { J = i; break; }
        }
        s_t = sVal[J];
        s_ti = sIdx[J];
    }

    // presence bitmask for the rep-penalty (only s==7 rows; block-uniform branch)
    if ((row & 7) == 7) {
        __syncthreads();
        for (int w = tid; w < MASK_WORDS_PER_B; w += 256) presRow[w] = 0u;
        __syncthreads();
        const int* bp = ids + (row >> 3) * L_;
#pragma unroll
        for (int k = 0; k < L_ / 256; ++k) {
            int t = bp[k * 256 + tid];
            atomicOr(&presRow[t >> 5], 1u << (t & 31));
        }
    }
    __syncthreads();

    // scatter kept values over the background (kept set is always a subset of
    // the candidate set: t >= kth >= TRAW/0.8 on the non-fallback path)
    float t = s_t;
    int tie = s_ti;
    float* orow = out + (size_t)row * V;
    const bool pen = (row & 7) == 7;
    for (int j = tid; j < cnt; j += 256) {
        float x = cX[j];
        int tok = cI[j];
        bool keep = (x > t) || (x == t && tok <= tie);
        if (keep) {
            float oo = x;   // exact v/0.8f, matches reference bits
            if (pen && ((presRow[tok >> 5] >> (tok & 31)) & 1u))
                oo = (oo < 0.0f) ? oo * 1.2f : oo * (1.0f / 1.2f);
            orow[tok] = oo;
        }
    }
}

// ---------------- safety fallback (ws too small; proven 3-kernel path) ----------------
#define CAND_CAP 4096
#define RT_THREADS 1024

__global__ __launch_bounds__(256) void mask_only_kernel(const int* __restrict__ ids,
                                                        unsigned* __restrict__ mask) {
    const int tid = threadIdx.x;
    const int b = blockIdx.x;
    __shared__ unsigned lds[MASK_WORDS_PER_B];
    for (int w = tid; w < MASK_WORDS_PER_B; w += 256) lds[w] = 0u;
    __syncthreads();
    const int* bp = ids + b * L_;
#pragma unroll
    for (int k = 0; k < L_ / 256; ++k) {
        int t = bp[k * 256 + tid];
        atomicOr(&lds[t >> 5], 1u << (t & 31));
    }
    __syncthreads();
    unsigned* mp = mask + b * MASK_WORDS_PER_B;
    for (int w = tid; w < MASK_WORDS_PER_B; w += 256) mp[w] = lds[w];
}

__global__ __launch_bounds__(RT_THREADS, 8) void row_thresh_kernel(
        const float* __restrict__ logits, uint4* __restrict__ rowParam) {
    const int tid = threadIdx.x;
    const int row = blockIdx.x;
    if (row >= ROWS) return;
    const float* rp = logits + (size_t)row * V;

    __shared__ float candV[CAND_CAP];
    __shared__ int   candI[CAND_CAP];
    __shared__ float sVal[TOP_CAP];
    __shared__ int   sIdx[TOP_CAP];
    __shared__ double sExp[TOP_CAP];
    __shared__ int s_cnt, s_M;
    __shared__ int s_red[RT_THREADS / 64];

    const unsigned mis = (unsigned)(((size_t)row * (size_t)V) & 3u);
    const int a0 = (int)((4u - mis) & 3u);
    const int nv = (V - a0) >> 2;
    const int tailStart = a0 + (nv << 2);
    const float4* vp = reinterpret_cast<const float4*>(rp + a0);

    float TR = 2.4f;
    int cnt = 0;
    for (int attempt = 0; attempt < 12; ++attempt) {
        if (tid == 0) s_cnt = 0;
        __syncthreads();
        for (int base = tid; base < nv; base += 4 * RT_THREADS) {
            int i1 = base + RT_THREADS, i2 = base + 2 * RT_THREADS, i3 = base + 3 * RT_THREADS;
            float4 a = vp[base];
            float4 b = vp[i1 < nv ? i1 : nv - 1];
            float4 c = vp[i2 < nv ? i2 : nv - 1];
            float4 d = vp[i3 < nv ? i3 : nv - 1];
            float va[16] = {a.x, a.y, a.z, a.w, b.x, b.y, b.z, b.w,
                            c.x, c.y, c.z, c.w, d.x, d.y, d.z, d.w};
            int ib[4] = {base, i1, i2, i3};
            bool ok[4] = {true, i1 < nv, i2 < nv, i3 < nv};
#pragma unroll
            for (int q = 0; q < 4; ++q) {
                if (!ok[q]) continue;
#pragma unroll
                for (int cc = 0; cc < 4; ++cc) {
                    float v = va[q * 4 + cc];
                    if (v >= TR) {
                        int p = atomicAdd(&s_cnt, 1);
                        if (p < CAND_CAP) { candV[p] = v / 0.8f; candI[p] = a0 + (ib[q] << 2) + cc; }
                    }
                }
            }
        }
        if (tid < a0) {
            float v = rp[tid];
            if (v >= TR) {
                int p = atomicAdd(&s_cnt, 1);
                if (p < CAND_CAP) { candV[p] = v / 0.8f; candI[p] = tid; }
            }
        }
        if (tid < V - tailStart) {
            float v = rp[tailStart + tid];
            if (v >= TR) {
                int p = atomicAdd(&s_cnt, 1);
                if (p < CAND_CAP) { candV[p] = v / 0.8f; candI[p] = tailStart + tid; }
            }
        }
        __syncthreads();
        cnt = s_cnt;
        if (cnt >= 50 && cnt <= CAND_CAP) break;
        if (cnt < 50) TR -= 1.2f; else TR += 1.2f;
        __syncthreads();
    }
    if (cnt > CAND_CAP) cnt = CAND_CAP;

    if (tid < TOP_CAP) { sVal[tid] = -3.4e38f; sIdx[tid] = 0x7FFFFFFF; }
    __syncthreads();

    {
        float v0 = (tid < cnt) ? candV[tid] : -3.4e38f;
        int i0 = (tid < cnt) ? candI[tid] : 0x7FFFFFFF;
        float v1 = (tid + RT_THREADS < cnt) ? candV[tid + RT_THREADS] : -3.4e38f;
        int i1 = (tid + RT_THREADS < cnt) ? candI[tid + RT_THREADS] : 0x7FFFFFFF;
        float v2 = (tid + 2 * RT_THREADS < cnt) ? candV[tid + 2 * RT_THREADS] : -3.4e38f;
        int i2 = (tid + 2 * RT_THREADS < cnt) ? candI[tid + 2 * RT_THREADS] : 0x7FFFFFFF;
        float v3 = (tid + 3 * RT_THREADS < cnt) ? candV[tid + 3 * RT_THREADS] : -3.4e38f;
        int i3 = (tid + 3 * RT_THREADS < cnt) ? candI[tid + 3 * RT_THREADS] : 0x7FFFFFFF;
        int r0 = 0, r1 = 0, r2 = 0, r3 = 0;
        for (int j = 0; j < cnt; ++j) {
            float w = candV[j];
            int wi = candI[j];
            r0 += (w > v0) || (w == v0 && wi < i0);
            r1 += (w > v1) || (w == v1 && wi < i1);
            r2 += (w > v2) || (w == v2 && wi < i2);
            r3 += (w > v3) || (w == v3 && wi < i3);
        }
        if (tid < cnt && r0 < TOP_CAP) { sVal[r0] = v0; sIdx[r0] = i0; }
        if (tid + RT_THREADS < cnt && r1 < TOP_CAP) { sVal[r1] = v1; sIdx[r1] = i1; }
        if (tid + 2 * RT_THREADS < cnt && r2 < TOP_CAP) { sVal[r2] = v2; sIdx[r2] = i2; }
        if (tid + 3 * RT_THREADS < cnt && r3 < TOP_CAP) { sVal[r3] = v3; sIdx[r3] = i3; }
    }
    __syncthreads();

    if (tid == 0) {
        float kth = sVal[49];
        int M = 50;
        while (M < TOP_CAP && sVal[M] == kth) ++M;
        s_M = M;
    }
    __syncthreads();
    int M = s_M;
    if (tid < M) sExp[tid] = exp((double)sVal[tid] - (double)sVal[0]);
    __syncthreads();

    if (tid == 0) {
        double denom = 0.0;
#pragma unroll 1
        for (int i = 0; i < M; ++i) denom += sExp[i];
        double cum = 0.0;
        int J = M - 1;
#pragma unroll 1
        for (int i = 0; i < M; ++i) {
            cum += sExp[i] / denom;
            if (cum > 0.9) { J = i; break; }
        }
        float t = sVal[J];
        float w = t * 0.8f;
        unsigned wb = __float_as_uint(w);
        unsigned lo = 0xFFFFFFFFu, hi = 0u;
        for (int d = -4; d <= 4; ++d) {
            unsigned ub = wb + (unsigned)d;
            if (__uint_as_float(ub) / 0.8f == t) { if (ub < lo) lo = ub; if (ub > hi) hi = ub; }
        }
        rowParam[row] = make_uint4(lo, hi, (unsigned)sIdx[J], 0u);
    }
}

__global__ __launch_bounds__(256) void apply_kernel(const float4* __restrict__ in4,
                                                    const uint4* __restrict__ rowParam,
                                                    const unsigned* __restrict__ mask,
                                                    float4* __restrict__ out4) {
    int gid = blockIdx.x * 256 + threadIdx.x;
    int i0 = gid << 1;
    if (i0 >= NVEC) return;
    float4 a = in4[i0];
    float4 b = in4[i0 + 1];
    unsigned e = (unsigned)i0 << 2;
    unsigned row = e / (unsigned)V;
    unsigned tok0 = e - row * (unsigned)V;
    uint4 p0 = rowParam[row];
    bool crosses = (tok0 + 7u >= (unsigned)V);
    uint4 p1 = crosses ? rowParam[row + 1] : p0;
    float xs[8] = {a.x, a.y, a.z, a.w, b.x, b.y, b.z, b.w};
    float o[8];
#pragma unroll
    for (int c = 0; c < 8; ++c) {
        unsigned tok = tok0 + (unsigned)c;
        unsigned r = row;
        uint4 pp = p0;
        if (tok >= (unsigned)V) { tok -= (unsigned)V; r = row + 1u; pp = p1; }
        float v = xs[c];
        float vlo = __uint_as_float(pp.x);
        float vhi = __uint_as_float(pp.y);
        bool keep = (v > vhi) || (v >= vlo && tok <= pp.z);
        float oo = keep ? v * 1.25f : NEG_INF;
        if ((r & 7u) == 7u) {
            unsigned w = mask[(r >> 3) * MASK_WORDS_PER_B + (tok >> 5)];
            if ((w >> (tok & 31u)) & 1u) oo = (oo < 0.0f) ? oo * 1.2f : oo * (1.0f / 1.2f);
        }
        o[c] = oo;
    }
    out4[i0] = make_float4(o[0], o[1], o[2], o[3]);
    out4[i0 + 1] = make_float4(o[4], o[5], o[6], o[7]);
}

extern "C" void kernel_launch(void* const* d_in, const int* in_sizes, int n_in,
                              void* d_out, int out_size, void* d_ws, size_t ws_size,
                              hipStream_t stream) {
    const float* logits = (const float*)d_in[0];
    const int* ids = (const int*)d_in[1];
    float* out = (float*)d_out;

    if (ws_size >= WS_NEED) {
        unsigned* bcnt = (unsigned*)((char*)d_ws + WS_BCNT);
        uint2* gcand = (uint2*)((char*)d_ws + WS_GCAND);
        // 2-kernel fast path: prep (pinned 7-deep MLP stream) -> select
        prep_kernel<<<GBLOCKS_G, 256, 0, stream>>>((const float4*)logits, ids, (float4*)out,
                                                   gcand, bcnt);
        select_kernel<<<ROWS, 256, 0, stream>>>(logits, ids, gcand, bcnt, out);
    } else {
        uint4* rowParam = (uint4*)((char*)d_ws + WS_ROWPARAM);
        unsigned* mask = (unsigned*)((char*)d_ws + WS_MASK);
        mask_only_kernel<<<B_, 256, 0, stream>>>(ids, mask);
        row_thresh_kernel<<<ROWS, RT_THREADS, 0, stream>>>(logits, rowParam);
        apply_kernel<<<(NVEC / 2 + 255) / 256, 256, 0, stream>>>((const float4*)logits, rowParam,
                                                                 mask, (float4*)out);
    }
}